// Round 5
// baseline (426.712 us; speedup 1.0000x reference)
//
#include <hip/hip_runtime.h>
#include <math.h>

// GRU-D, diagonal weights: independent scalar recurrence per (b,f) over T.
// R6: R2/R4/R5 all proved a REGISTER-resident streaming double-buffer gets
// dissolved (R5's VGPR=44 < 48 live payload floats => allocator demoted the
// asm-load destinations to scratch; spilling an outstanding load's dest
// forces a wait -> pipeline collapsed to load->wait->use; all three rounds
// identical at 155-185us, VALUBusy ~27%, HBM ~27%). Fix: put the in-flight
// data in LDS via global_load_lds (HBM->LDS DMA, NO VGPR destination -- the
// register allocator has nothing to dissolve). With 1 wave/SIMD each wave
// loads and consumes its OWN 64-feature LDS region: no __syncthreads, no
// barrier drain, ordering purely by counted inline-asm vmcnt (m201 pattern:
// compiler inserts no implicit drain between global_load_lds and ds_read).
//
// Phase c: [s_waitcnt vmcnt(32)] [compute chunk c from LDS: 8 nt-stores]
// [issue 24 global_load_lds for chunk c+2]. Newer-than-chunk-c at the wait
// = 8 stores + 24 loads = 32 (encodable, constant). Prefetch cover = one
// full compute phase (~800cy) ~ HBM latency.

#define TT 512
#define BB 256
#define FF 256
#define BF (BB * FF)        // elements per time step per array
#define CH 8                // steps per LDS chunk
#define NCH (TT / CH)       // 64 chunks

__device__ __forceinline__ float fast_sigmoid(float x) {
    return __builtin_amdgcn_rcpf(1.0f + __expf(-x));
}
__device__ __forceinline__ float fast_tanh(float x) {
    return fmaf(-2.0f, __builtin_amdgcn_rcpf(1.0f + __expf(2.0f * x)), 1.0f);
}

typedef __attribute__((address_space(1))) const void gconst_void;
typedef __attribute__((address_space(3))) void lds_void;

// HBM -> LDS direct copy: lane i's 4B from its own global address lands at
// ldsbase + 4*i (wave-uniform LDS base + lane*size). No VGPR destination.
__device__ __forceinline__ void gload_lds4(const float* g, float* l) {
    __builtin_amdgcn_global_load_lds((gconst_void*)g, (lds_void*)l, 4, 0, 0);
}

// Counted wait + scheduler fence (fence mandatory: stops ds_reads/stores
// from being scheduled above the asm wait).
#define VMWAIT(N)                                                   \
    do {                                                            \
        asm volatile("s_waitcnt vmcnt(" #N ")" ::: "memory");       \
        __builtin_amdgcn_sched_barrier(0);                          \
    } while (0)

__global__ __launch_bounds__(256, 1) void grud_kernel(
    const float* __restrict__ X, const float* __restrict__ Mask,
    const float* __restrict__ Delta,
    const float* __restrict__ x_mean,
    const float* __restrict__ w_dg_x, const float* __restrict__ b_dg_x,
    const float* __restrict__ w_dg_h, const float* __restrict__ b_dg_h,
    const float* __restrict__ w_xz, const float* __restrict__ u_hz,
    const float* __restrict__ b_z,
    const float* __restrict__ w_xr, const float* __restrict__ u_hr,
    const float* __restrict__ b_r,
    const float* __restrict__ w_xh, const float* __restrict__ u_hh,
    const float* __restrict__ v_mh, const float* __restrict__ b_h,
    float* __restrict__ out)
{
    // [wave][buf][arr][step][lane] : 4*2*3*8*64*4B = 48 KiB
    __shared__ float lds[4][2][3][CH][64];

    const int tid = threadIdx.x;        // 0..255 : feature index f
    const int w   = tid >> 6;           // wave id 0..3
    const int ln  = tid & 63;           // lane id
    const int b   = blockIdx.x;         // batch index

    const size_t base = (size_t)b * FF + tid;
    const float* __restrict__ px = X     + base;   // per-lane global addr
    const float* __restrict__ pm = Mask  + base;
    const float* __restrict__ pd = Delta + base;
    float* __restrict__ ob = out + (size_t)b * TT * FF + tid;

    // per-feature parameters (coalesced, loaded once; trivial VGPR budget)
    const float xm  = x_mean[tid];
    const float wdx = w_dg_x[tid], bdx = b_dg_x[tid];
    const float wdh = w_dg_h[tid], bdh = b_dg_h[tid];
    const float wxz = w_xz[tid],   uhz = u_hz[tid], bz = b_z[tid];
    const float wxr = w_xr[tid],   uhr = u_hr[tid], br = b_r[tid];
    const float wxh = w_xh[tid],   uhh = u_hh[tid];
    const float vmh = v_mh[tid],   bh  = b_h[tid];

    // Resolve the param-load waits here, not inside the pipeline.
    asm volatile("" :: "v"(xm), "v"(wdx), "v"(bdx), "v"(wdh), "v"(bdh),
                       "v"(wxz), "v"(uhz), "v"(bz), "v"(wxr), "v"(uhr),
                       "v"(br), "v"(wxh), "v"(uhh), "v"(vmh), "v"(bh));
    float h = 0.0f;

    // issue one chunk (24 global_load_lds) into buffer `buf`
    auto issuec = [&](int buf, int c) {
        const size_t o = (size_t)c * CH * BF;
        #pragma unroll
        for (int s = 0; s < CH; ++s)
            gload_lds4(px + o + (size_t)s * BF, &lds[w][buf][0][s][0]);
        #pragma unroll
        for (int s = 0; s < CH; ++s)
            gload_lds4(pm + o + (size_t)s * BF, &lds[w][buf][1][s][0]);
        #pragma unroll
        for (int s = 0; s < CH; ++s)
            gload_lds4(pd + o + (size_t)s * BF, &lds[w][buf][2][s][0]);
        __builtin_amdgcn_sched_barrier(0);
    };

    // compute one chunk from LDS (ds_read_b32, lane-linear: conflict-free)
    auto computec = [&](int buf, int c) {
        float* op = ob + (size_t)c * CH * FF;
        #pragma unroll
        for (int s = 0; s < CH; ++s) {
            float x = lds[w][buf][0][s][ln];
            float m = lds[w][buf][1][s][ln];
            float d = lds[w][buf][2][s][ln];
            float gx = __expf(-fmaxf(0.0f, fmaf(wdx, d, bdx)));
            float gh = __expf(-fmaxf(0.0f, fmaf(wdh, d, bdh)));
            float xhat = fmaf(gx, x, (1.0f - gx) * xm);
            x = fmaf(m, x, (1.0f - m) * xhat);
            h = gh * h;
            float z  = fast_sigmoid(fmaf(wxz, x, fmaf(uhz, h, bz)));
            float r  = fast_sigmoid(fmaf(wxr, x, fmaf(uhr, h, br)));
            float ht = fast_tanh(fmaf(wxh, x, fmaf(uhh, r * h, fmaf(vmh, m, bh))));
            h = fmaf(z, ht - h, h);               // (1-z)*h + z*ht
            __builtin_nontemporal_store(h, op + (size_t)s * FF);
        }
    };

    // ---- prologue: two chunks in flight ----
    issuec(0, 0);
    issuec(1, 1);
    VMWAIT(24);                 // ld(0) done; ld(1) still flying
    computec(0, 0);
    issuec(0, 2);

    // ---- steady state: chunk c in buf c&1, uniform vmcnt(32) ----
    // at each wait: newer = 8 stores (prev phase) + 24 loads (prev issue)
    for (int c = 1; c <= NCH - 3; ++c) {          // c = 1..61
        VMWAIT(32);
        computec(c & 1, c);
        issuec(c & 1, c + 2);                     // c+2 <= 63
    }

    // ---- tail: chunks 62, 63 already issued ----
    VMWAIT(32);                 // newer: st(61) 8 + ld(63) 24
    computec(0, NCH - 2);       // 62
    VMWAIT(8);                  // newer: st(62) 8
    computec(1, NCH - 1);       // 63

    // second output: last hidden state [B, H]
    out[(size_t)BB * TT * FF + (size_t)b * FF + tid] = h;
}

extern "C" void kernel_launch(void* const* d_in, const int* in_sizes, int n_in,
                              void* d_out, int out_size, void* d_ws, size_t ws_size,
                              hipStream_t stream) {
    const float* X      = (const float*)d_in[0];
    const float* Mask   = (const float*)d_in[1];
    const float* Delta  = (const float*)d_in[2];
    const float* x_mean = (const float*)d_in[3];
    const float* w_dg_x = (const float*)d_in[4];
    const float* b_dg_x = (const float*)d_in[5];
    const float* w_dg_h = (const float*)d_in[6];
    const float* b_dg_h = (const float*)d_in[7];
    const float* w_xz   = (const float*)d_in[8];
    const float* u_hz   = (const float*)d_in[9];
    const float* b_z    = (const float*)d_in[10];
    const float* w_xr   = (const float*)d_in[11];
    const float* u_hr   = (const float*)d_in[12];
    const float* b_r    = (const float*)d_in[13];
    const float* w_xh   = (const float*)d_in[14];
    const float* u_hh   = (const float*)d_in[15];
    const float* v_mh   = (const float*)d_in[16];
    const float* b_h    = (const float*)d_in[17];
    float* out = (float*)d_out;

    grud_kernel<<<BB, 256, 0, stream>>>(
        X, Mask, Delta, x_mean, w_dg_x, b_dg_x, w_dg_h, b_dg_h,
        w_xz, u_hz, b_z, w_xr, u_hr, b_r, w_xh, u_hh, v_mh, b_h, out);
}